// Round 8
// baseline (156.964 us; speedup 1.0000x reference)
//
#include <hip/hip_runtime.h>
#include <hip/hip_fp16.h>

#define DDIM 64
#define MAXNS 2048          // max slices (nodes/256) handled by the new path
#define PART_TPB 256
#define PART_EPT 16
#define PART_EPB (PART_TPB * PART_EPT)   // 4096 edges per block

__device__ __forceinline__ float atomAddF(float* p, float v) {
    return unsafeAtomicAdd(p, v);   // HW global_atomic_add_f32 on gfx950
}

// ================= CSR BUILD: two-level counting sort by dst>>8 =================

__global__ void slice_count_kernel(const int* __restrict__ dst, int* __restrict__ sliceCnt,
                                   int nE, int NS) {
    __shared__ int lh[MAXNS];
    int t = threadIdx.x;
    int blockBase = blockIdx.x * PART_EPB;
    for (int i = t; i < NS; i += PART_TPB) lh[i] = 0;
    __syncthreads();
    #pragma unroll
    for (int c = 0; c < 4; ++c) {
        int e0 = blockBase + (c * PART_TPB + t) * 4;
        if (e0 + 3 < nE) {
            int4 b = *(const int4*)(dst + e0);
            atomicAdd(&lh[b.x >> 8], 1); atomicAdd(&lh[b.y >> 8], 1);
            atomicAdd(&lh[b.z >> 8], 1); atomicAdd(&lh[b.w >> 8], 1);
        } else {
            for (int j = 0; j < 4; ++j) {
                int e = e0 + j;
                if (e < nE) atomicAdd(&lh[dst[e] >> 8], 1);
            }
        }
    }
    __syncthreads();
    for (int i = t; i < NS; i += PART_TPB)
        if (lh[i]) atomicAdd(&sliceCnt[i], lh[i]);
}

__global__ void slice_scan_wp_kernel(int* __restrict__ scnt, int* __restrict__ sbase,
                                     int NS, int nE,
                                     const float* __restrict__ W, const float* __restrict__ lamda_p,
                                     const int* __restrict__ layer_p, float* __restrict__ Wp) {
    __shared__ int sdata[512];
    int t = threadIdx.x;
    int base = t * 4;
    int v[4];
    #pragma unroll
    for (int j = 0; j < 4; ++j) {
        int idx = base + j;
        v[j] = (idx < NS) ? scnt[idx] : 0;
    }
    int local = v[0] + v[1] + v[2] + v[3];
    sdata[t] = local;
    __syncthreads();
    for (int off = 1; off < 512; off <<= 1) {
        int y = (t >= off) ? sdata[t - off] : 0;
        __syncthreads();
        sdata[t] += y;
        __syncthreads();
    }
    int run = sdata[t] - local;
    #pragma unroll
    for (int j = 0; j < 4; ++j) {
        int idx = base + j;
        if (idx < NS) { sbase[idx] = run; scnt[idx] = run; }
        run += v[j];
    }
    if (t == 0) sbase[NS] = nE;

    float lam = lamda_p[0];
    int lb = layer_p[0];
    float layerf = (lb > 0 && lb < (1 << 23)) ? (float)lb : __int_as_float(lb);
    float beta = logf(lam / layerf + 1.0f);
    for (int i = t; i < DDIM * DDIM; i += 512) {
        int k = i >> 6, d = i & 63;
        float w = beta * W[i];
        if (k == d) w += (1.0f - beta);
        Wp[i] = w;
    }
}

__global__ void partition_kernel(const int* __restrict__ src, const int* __restrict__ dst,
                                 int* __restrict__ cursor, unsigned* __restrict__ staging,
                                 int nE, int NS) {
    __shared__ int lh[MAXNS];
    __shared__ int lbase[MAXNS];
    int t = threadIdx.x;
    int blockBase = blockIdx.x * PART_EPB;
    for (int i = t; i < NS; i += PART_TPB) lh[i] = 0;
    __syncthreads();

    int se[PART_EPT]; int de[PART_EPT];
    #pragma unroll
    for (int c = 0; c < 4; ++c) {
        int e0 = blockBase + (c * PART_TPB + t) * 4;
        if (e0 + 3 < nE) {
            int4 a = *(const int4*)(src + e0);
            int4 b = *(const int4*)(dst + e0);
            se[4*c+0] = a.x; se[4*c+1] = a.y; se[4*c+2] = a.z; se[4*c+3] = a.w;
            de[4*c+0] = b.x; de[4*c+1] = b.y; de[4*c+2] = b.z; de[4*c+3] = b.w;
        } else {
            #pragma unroll
            for (int j = 0; j < 4; ++j) {
                int e = e0 + j;
                se[4*c+j] = (e < nE) ? src[e] : 0;
                de[4*c+j] = (e < nE) ? dst[e] : -1;
            }
        }
    }
    #pragma unroll
    for (int k = 0; k < PART_EPT; ++k)
        if (de[k] >= 0) atomicAdd(&lh[de[k] >> 8], 1);
    __syncthreads();
    for (int i = t; i < NS; i += PART_TPB) {
        int c = lh[i];
        if (c) lbase[i] = atomicAdd(&cursor[i], c);
        lh[i] = 0;
    }
    __syncthreads();
    #pragma unroll
    for (int k = 0; k < PART_EPT; ++k) {
        int d = de[k];
        if (d >= 0) {
            int sl = d >> 8;
            int off = atomicAdd(&lh[sl], 1);
            staging[lbase[sl] + off] = ((unsigned)se[k] << 8) | (unsigned)(d & 255);
        }
    }
}

// Pass 4 (t1/t2 tiers): rowdeg + normv + packed pidx scatter.
__global__ void bin_fill_kernel(const unsigned* __restrict__ staging, const int* __restrict__ sbase,
                                int2* __restrict__ rowdeg, float* __restrict__ normv,
                                unsigned* __restrict__ pidx, int nN) {
    __shared__ int cnt[256];
    __shared__ int pos[256];
    int s = blockIdx.x;
    int t = threadIdx.x;
    int b0 = sbase[s], b1 = sbase[s + 1];
    cnt[t] = 0;
    __syncthreads();
    for (int j = b0 + t; j < b1; j += 256) {
        unsigned p = staging[j];
        atomicAdd(&cnt[p & 255], 1);
    }
    __syncthreads();
    int c = cnt[t];
    pos[t] = c;
    __syncthreads();
    for (int off = 1; off < 256; off <<= 1) {
        int y = (t >= off) ? pos[t - off] : 0;
        __syncthreads();
        pos[t] += y;
        __syncthreads();
    }
    int inc = pos[t];
    int exc = inc - c;
    int node = (s << 8) + t;
    if (node < nN) {
        rowdeg[node] = make_int2(b0 + inc, c);
        normv[node] = rsqrtf(fmaxf((float)c, 1.0f));
    }
    pos[t] = b0 + exc;
    __syncthreads();
    for (int j = b0 + t; j < b1; j += 256) {
        unsigned p = staging[j];
        int q = atomicAdd(&pos[p & 255], 1);
        pidx[q] = p;              // packed: src<<8 | dstLow
    }
}

// Pass 4 (t0 tier, staging NOT aliased with featS): bin_fill + fused featS scale.
// Block <-> slice <-> 256 nodes mapping means the norm for this slice's nodes is
// already in LDS; appending the fp16 scale here saves a kernel launch + the
// normv re-read of the separate scale pass.
__global__ void bin_fill_scale_kernel(const unsigned* __restrict__ staging, const int* __restrict__ sbase,
                                      int2* __restrict__ rowdeg, float* __restrict__ normv,
                                      unsigned* __restrict__ pidx,
                                      const float4* __restrict__ feat4, uint2* __restrict__ featS2,
                                      int nN) {
    __shared__ int cnt[256];
    __shared__ int pos[256];
    __shared__ float narr[256];
    int s = blockIdx.x;
    int t = threadIdx.x;
    int b0 = sbase[s], b1 = sbase[s + 1];
    cnt[t] = 0;
    __syncthreads();
    for (int j = b0 + t; j < b1; j += 256) {
        unsigned p = staging[j];
        atomicAdd(&cnt[p & 255], 1);
    }
    __syncthreads();
    int c = cnt[t];
    pos[t] = c;
    __syncthreads();
    for (int off = 1; off < 256; off <<= 1) {
        int y = (t >= off) ? pos[t - off] : 0;
        __syncthreads();
        pos[t] += y;
        __syncthreads();
    }
    int inc = pos[t];
    int exc = inc - c;
    int node = (s << 8) + t;
    float nv = rsqrtf(fmaxf((float)c, 1.0f));
    narr[t] = nv;
    if (node < nN) {
        rowdeg[node] = make_int2(b0 + inc, c);
        normv[node] = nv;
    }
    pos[t] = b0 + exc;
    __syncthreads();                    // also publishes narr[]
    for (int j = b0 + t; j < b1; j += 256) {
        unsigned p = staging[j];
        int q = atomicAdd(&pos[p & 255], 1);
        pidx[q] = p;
    }
    // fused featS(fp16) = feat * norm for this slice's 256 nodes (coalesced)
    for (int i = t; i < 256 * 16; i += 256) {
        int nl = i >> 4, rr = i & 15;
        int nd = (s << 8) + nl;
        if (nd < nN) {
            float sc = narr[nl];
            float4 v = feat4[(size_t)nd * 16 + rr];
            __half2 h0 = __floats2half2_rn(v.x * sc, v.y * sc);
            __half2 h1 = __floats2half2_rn(v.z * sc, v.w * sc);
            uint2 u;
            u.x = *(unsigned*)&h0;
            u.y = *(unsigned*)&h1;
            featS2[(size_t)nd * 16 + rr] = u;
        }
    }
}

// featS(fp16) = feat * norm[node] (t1 tier, staging aliased -> separate pass)
__global__ void scale_kernel(const float4* __restrict__ feat4, const float* __restrict__ normv,
                             uint2* __restrict__ featS2, int nN) {
    int b = blockIdx.x, t = threadIdx.x;
    int node = b * 16 + (t >> 4);
    int r = t & 15;
    if (node < nN) {
        float nv = normv[node];
        float4 v = feat4[(size_t)node * 16 + r];
        __half2 h0 = __floats2half2_rn(v.x * nv, v.y * nv);
        __half2 h1 = __floats2half2_rn(v.z * nv, v.w * nv);
        uint2 u;
        u.x = *(unsigned*)&h0;
        u.y = *(unsigned*)&h1;
        featS2[(size_t)node * 16 + r] = u;
    }
}

// Accumulate macros (parameter names must NOT collide with .x/.y/.z/.w tokens)
#define ACC_H(uu, ww) { \
    float2 a0 = __half22float2(*(const __half2*)&(uu).x); \
    float2 a1 = __half22float2(*(const __half2*)&(uu).y); \
    acc.x = fmaf(a0.x, ww, acc.x); acc.y = fmaf(a0.y, ww, acc.y); \
    acc.z = fmaf(a1.x, ww, acc.z); acc.w = fmaf(a1.y, ww, acc.w); }
#define ACC_F(vv, ww) { \
    acc.x = fmaf((vv).x, ww, acc.x); acc.y = fmaf((vv).y, ww, acc.y); \
    acc.z = fmaf((vv).z, ww, acc.z); acc.w = fmaf((vv).w, ww, acc.w); }

// ---------------- fused gather + epilogue (wave per node, 4x16 lane layout) ----------------
// UNCHANGED from r7 (verified 84us — empirically at the random-access wall:
// bytes/2, requests/2, occupancy x2, ILP x1.5 all null across r1-r7).
template<bool HALF>
__global__ void gather3_kernel(const void* __restrict__ featv_, const float4* __restrict__ feat04,
                               const float* __restrict__ normv, const int2* __restrict__ rowdeg,
                               const unsigned* __restrict__ pidx,
                               const float* __restrict__ Wp, const float* __restrict__ alpha_p,
                               float4* __restrict__ out4, int nN, int nE) {
    __shared__ float4 sW[DDIM * 16];   // 16 KiB, XOR-swizzled
    const float4* Wp4 = (const float4*)Wp;
    for (int i = threadIdx.x; i < DDIM * 16; i += blockDim.x) {
        sW[(i & ~15) | ((i & 15) ^ ((i >> 8) & 3))] = Wp4[i];
    }
    __syncthreads();

    const float4* featF = (const float4*)featv_;
    const uint2*  featH = (const uint2*)featv_;

    int lane = threadIdx.x & 63;
    int w = threadIdx.x >> 6;
    int g = lane >> 4;
    int r = lane & 15;
    float alpha = alpha_p[0];
    int step = gridDim.x * 4;
    int nEm1 = nE - 1;

    int n = blockIdx.x * 4 + w;
    if (n >= nN) return;

    int2 rd = rowdeg[n];
    int pj = rd.x - rd.y + lane;
    unsigned pv = pidx[pj > nEm1 ? nEm1 : (pj < 0 ? 0 : pj)];
    int n1 = n + step;
    int2 rd1 = make_int2(0, 0);
    if (n1 < nN) rd1 = rowdeg[n1];

    while (true) {
        unsigned pv1 = 0u;
        if (n1 < nN) {
            int pj1 = rd1.x - rd1.y + lane;
            pv1 = pidx[pj1 > nEm1 ? nEm1 : (pj1 < 0 ? 0 : pj1)];
        }
        int n2 = n1 + step;
        int2 rd2 = make_int2(0, 0);
        if (n2 < nN) rd2 = rowdeg[n2];

        float4 f0 = feat04[(size_t)n * 16 + r];

        int end = rd.x;
        int start = end - rd.y;

        float4 acc = make_float4(0.f, 0.f, 0.f, 0.f);

        for (int j0 = start; j0 < end; j0 += 64) {
            int m = end - j0; if (m > 64) m = 64;
            unsigned pcur;
            if (j0 == start) {
                pcur = pv;
            } else {
                int cj = j0 + lane;
                pcur = pidx[cj > nEm1 ? nEm1 : cj];
            }
            int sIdx = (int)(pcur >> 8);
            float nv = 1.0f;
            if (!HALF) nv = normv[sIdx];
            int nt = (m + 3) >> 2;
            int t = 0;
            for (; t + 3 <= nt; t += 3) {
                int e0 = 4 * t + g, e1 = e0 + 4, e2 = e0 + 8;
                int s0 = __shfl(sIdx, e0, 64);
                int s1 = __shfl(sIdx, e1, 64);
                int s2 = __shfl(sIdx, e2, 64);
                float w0 = (e0 < m) ? 1.0f : 0.0f;
                float w1 = (e1 < m) ? 1.0f : 0.0f;
                float w2 = (e2 < m) ? 1.0f : 0.0f;
                if (HALF) {
                    uint2 ua = featH[(size_t)s0 * 16 + r];
                    uint2 ub = featH[(size_t)s1 * 16 + r];
                    uint2 uc = featH[(size_t)s2 * 16 + r];
                    ACC_H(ua, w0) ACC_H(ub, w1) ACC_H(uc, w2)
                } else {
                    w0 *= __shfl(nv, e0, 64);
                    w1 *= __shfl(nv, e1, 64);
                    w2 *= __shfl(nv, e2, 64);
                    float4 fa = featF[(size_t)s0 * 16 + r];
                    float4 fb = featF[(size_t)s1 * 16 + r];
                    float4 fc = featF[(size_t)s2 * 16 + r];
                    ACC_F(fa, w0) ACC_F(fb, w1) ACC_F(fc, w2)
                }
            }
            for (; t + 2 <= nt; t += 2) {
                int e0 = 4 * t + g, e1 = e0 + 4;
                int s0 = __shfl(sIdx, e0, 64);
                int s1 = __shfl(sIdx, e1, 64);
                float w0 = (e0 < m) ? 1.0f : 0.0f;
                float w1 = (e1 < m) ? 1.0f : 0.0f;
                if (HALF) {
                    uint2 ua = featH[(size_t)s0 * 16 + r];
                    uint2 ub = featH[(size_t)s1 * 16 + r];
                    ACC_H(ua, w0) ACC_H(ub, w1)
                } else {
                    w0 *= __shfl(nv, e0, 64);
                    w1 *= __shfl(nv, e1, 64);
                    float4 fa = featF[(size_t)s0 * 16 + r];
                    float4 fb = featF[(size_t)s1 * 16 + r];
                    ACC_F(fa, w0) ACC_F(fb, w1)
                }
            }
            for (; t < nt; ++t) {
                int e = 4 * t + g;
                int s = __shfl(sIdx, e, 64);
                float w0 = (e < m) ? 1.0f : 0.0f;
                if (HALF) {
                    uint2 ua = featH[(size_t)s * 16 + r];
                    ACC_H(ua, w0)
                } else {
                    w0 *= __shfl(nv, e, 64);
                    float4 fa = featF[(size_t)s * 16 + r];
                    ACC_F(fa, w0)
                }
            }
        }

        acc.x += __shfl_xor(acc.x, 16, 64); acc.y += __shfl_xor(acc.y, 16, 64);
        acc.z += __shfl_xor(acc.z, 16, 64); acc.w += __shfl_xor(acc.w, 16, 64);
        acc.x += __shfl_xor(acc.x, 32, 64); acc.y += __shfl_xor(acc.y, 32, 64);
        acc.z += __shfl_xor(acc.z, 32, 64); acc.w += __shfl_xor(acc.w, 32, 64);

        float sn = normv[n] * (1.0f - alpha);
        float4 fs;
        fs.x = fmaf(acc.x, sn, f0.x * alpha);
        fs.y = fmaf(acc.y, sn, f0.y * alpha);
        fs.z = fmaf(acc.z, sn, f0.z * alpha);
        fs.w = fmaf(acc.w, sn, f0.w * alpha);

        float4 res = make_float4(0.f, 0.f, 0.f, 0.f);
        #pragma unroll
        for (int kk = 0; kk < 16; ++kk) {
            int srcLane = 4 * g + (kk >> 2);
            float fscomp = ((kk & 3) == 0) ? fs.x : ((kk & 3) == 1) ? fs.y
                         : ((kk & 3) == 2) ? fs.z : fs.w;
            float fsk = __shfl(fscomp, srcLane, 64);
            float4 wv = sW[(16 * g + kk) * 16 + (r ^ g)];
            res.x = fmaf(fsk, wv.x, res.x);
            res.y = fmaf(fsk, wv.y, res.y);
            res.z = fmaf(fsk, wv.z, res.z);
            res.w = fmaf(fsk, wv.w, res.w);
        }
        res.x += __shfl_xor(res.x, 16, 64); res.y += __shfl_xor(res.y, 16, 64);
        res.z += __shfl_xor(res.z, 16, 64); res.w += __shfl_xor(res.w, 16, 64);
        res.x += __shfl_xor(res.x, 32, 64); res.y += __shfl_xor(res.y, 32, 64);
        res.z += __shfl_xor(res.z, 32, 64); res.w += __shfl_xor(res.w, 32, 64);

        if (g == 0) out4[(size_t)n * 16 + r] = res;

        if (n1 >= nN) break;
        n = n1; rd = rd1; pv = pv1;
        n1 = n2; rd1 = rd2;
    }
}

// ================= OLD CSR BUILD (fallback tier) =================

__global__ void deg_int_kernel(const int* __restrict__ dst, int* __restrict__ degI, int nE) {
    int i = blockIdx.x * blockDim.x + threadIdx.x;
    int base = i * 4;
    if (base + 3 < nE) {
        int4 d = *(const int4*)(dst + base);
        atomicAdd(&degI[d.x], 1); atomicAdd(&degI[d.y], 1);
        atomicAdd(&degI[d.z], 1); atomicAdd(&degI[d.w], 1);
    } else {
        for (int j = base; j < nE; ++j) atomicAdd(&degI[dst[j]], 1);
    }
}

#define SCAN_BLOCK 256
#define SCAN_CHUNK 1024

__global__ void scan1_kernel(const int* __restrict__ degI, int* __restrict__ row_start,
                             float* __restrict__ normv, int* __restrict__ blockSums, int nN) {
    __shared__ int sdata[SCAN_BLOCK];
    int t = threadIdx.x;
    int base = blockIdx.x * SCAN_CHUNK + t * 4;
    int v[4];
    #pragma unroll
    for (int j = 0; j < 4; ++j) {
        int idx = base + j;
        v[j] = (idx < nN) ? degI[idx] : 0;
    }
    int local = v[0] + v[1] + v[2] + v[3];
    sdata[t] = local;
    __syncthreads();
    for (int off = 1; off < SCAN_BLOCK; off <<= 1) {
        int y = (t >= off) ? sdata[t - off] : 0;
        __syncthreads();
        sdata[t] += y;
        __syncthreads();
    }
    int inc = sdata[t];
    int exc = inc - local;
    if (t == SCAN_BLOCK - 1) blockSums[blockIdx.x] = inc;
    int run = exc;
    #pragma unroll
    for (int j = 0; j < 4; ++j) {
        int idx = base + j;
        if (idx < nN) {
            row_start[idx] = run;
            normv[idx] = rsqrtf(fmaxf((float)v[j], 1.0f));
        }
        run += v[j];
    }
}

__global__ void scan2_wp_kernel(int* __restrict__ blockSums, int nb,
                                const float* __restrict__ W, const float* __restrict__ lamda_p,
                                const int* __restrict__ layer_p, float* __restrict__ Wp) {
    __shared__ int sdata[SCAN_BLOCK];
    int t = threadIdx.x;
    int v = (t < nb) ? blockSums[t] : 0;
    sdata[t] = v;
    __syncthreads();
    for (int off = 1; off < SCAN_BLOCK; off <<= 1) {
        int y = (t >= off) ? sdata[t - off] : 0;
        __syncthreads();
        sdata[t] += y;
        __syncthreads();
    }
    if (t < nb) blockSums[t] = sdata[t] - v;

    float lam = lamda_p[0];
    int lb = layer_p[0];
    float layerf = (lb > 0 && lb < (1 << 23)) ? (float)lb : __int_as_float(lb);
    float beta = logf(lam / layerf + 1.0f);
    for (int i = t; i < DDIM * DDIM; i += SCAN_BLOCK) {
        int k = i >> 6, d = i & 63;
        float w = beta * W[i];
        if (k == d) w += (1.0f - beta);
        Wp[i] = w;
    }
}

// add block offsets to row_start, build rowdeg, optionally produce featS(fp16)
__global__ void scan3_scale_kernel(int* __restrict__ row_start, const int* __restrict__ blockSums,
                                   const int* __restrict__ degI,
                                   const float4* __restrict__ feat4, const float* __restrict__ normv,
                                   uint2* __restrict__ featS2, int2* __restrict__ rowdeg, int nN) {
    int b = blockIdx.x, t = threadIdx.x;
    int node = b * 16 + (t >> 4);
    int r = t & 15;
    if (featS2 != nullptr && node < nN) {
        float nv = normv[node];
        float4 v = feat4[(size_t)node * 16 + r];
        __half2 h0 = __floats2half2_rn(v.x * nv, v.y * nv);
        __half2 h1 = __floats2half2_rn(v.z * nv, v.w * nv);
        uint2 u;
        u.x = *(unsigned*)&h0;
        u.y = *(unsigned*)&h1;
        featS2[(size_t)node * 16 + r] = u;
    }
    if (t < 16) {
        int n2 = b * 16 + t;
        if (n2 < nN) {
            int rs = row_start[n2] + blockSums[n2 >> 10];
            int dg = degI[n2];
            row_start[n2] = rs;
            rowdeg[n2] = make_int2(rs + dg, dg);   // row END after fill
        }
    }
}

// packed fill: pidx entry = src<<8 | dstLow
__global__ void fill_kernel(const int* __restrict__ src, const int* __restrict__ dst,
                            int* __restrict__ row_start, unsigned* __restrict__ pidx, int nE) {
    int i = blockIdx.x * blockDim.x + threadIdx.x;
    int base = i * 4;
    if (base + 3 < nE) {
        int4 s = *(const int4*)(src + base);
        int4 d = *(const int4*)(dst + base);
        pidx[atomicAdd(&row_start[d.x], 1)] = ((unsigned)s.x << 8) | (unsigned)(d.x & 255);
        pidx[atomicAdd(&row_start[d.y], 1)] = ((unsigned)s.y << 8) | (unsigned)(d.y & 255);
        pidx[atomicAdd(&row_start[d.z], 1)] = ((unsigned)s.z << 8) | (unsigned)(d.z & 255);
        pidx[atomicAdd(&row_start[d.w], 1)] = ((unsigned)s.w << 8) | (unsigned)(d.w & 255);
    } else {
        for (int j = base; j < nE; ++j) {
            int tt = dst[j];
            int p = atomicAdd(&row_start[tt], 1);
            pidx[p] = ((unsigned)src[j] << 8) | (unsigned)(tt & 255);
        }
    }
}

// ---------------- last-resort fallback (atomic scatter path) ----------------

__global__ void deg_kernel(const int* __restrict__ dst, float* __restrict__ degs, int nE) {
    int i = blockIdx.x * blockDim.x + threadIdx.x;
    if (i < nE) atomAddF(&degs[dst[i]], 1.0f);
}

__global__ void norm_kernel(float* degs, int nN) {
    int i = blockIdx.x * blockDim.x + threadIdx.x;
    if (i < nN) degs[i] = rsqrtf(fmaxf(degs[i], 1.0f));
}

__global__ void wp_kernel(const float* __restrict__ W, const float* __restrict__ lamda_p,
                          const int* __restrict__ layer_p, float* __restrict__ Wp) {
    int i = blockIdx.x * blockDim.x + threadIdx.x;
    if (i < DDIM * DDIM) {
        float lam = lamda_p[0];
        int lb = layer_p[0];
        float layerf = (lb > 0 && lb < (1 << 23)) ? (float)lb : __int_as_float(lb);
        float beta = logf(lam / layerf + 1.0f);
        int k = i >> 6, d = i & 63;
        float w = beta * W[i];
        if (k == d) w += (1.0f - beta);
        Wp[i] = w;
    }
}

__global__ void scatter_kernel(const float* __restrict__ feat, const float* __restrict__ norm,
                               const int* __restrict__ src, const int* __restrict__ dst,
                               float* __restrict__ accum, int nE) {
    long long gid = (long long)blockIdx.x * blockDim.x + threadIdx.x;
    int e = (int)(gid >> 6);
    int d = (int)(gid & 63);
    if (e < nE) {
        int s = src[e];
        int t = dst[e];
        float v = feat[(size_t)s * DDIM + d] * norm[s];
        atomAddF(&accum[(size_t)t * DDIM + d], v);
    }
}

__global__ void final_kernel(float* __restrict__ out, const float* __restrict__ feat0,
                             const float* __restrict__ norm, const float* __restrict__ Wp,
                             const float* __restrict__ alpha_p, int nN) {
    __shared__ float sW[DDIM * DDIM];
    for (int i = threadIdx.x; i < DDIM * DDIM; i += blockDim.x) sW[i] = Wp[i];
    __syncthreads();
    float alpha = alpha_p[0];
    int lane = threadIdx.x & 63;
    int w = threadIdx.x >> 6;
    int wavesPerBlock = blockDim.x >> 6;
    int nGroups = (nN + wavesPerBlock - 1) / wavesPerBlock;
    for (int gi = blockIdx.x; gi < nGroups; gi += gridDim.x) {
        int n = gi * wavesPerBlock + w;
        bool valid = n < nN;
        float fs = 0.0f;
        if (valid) {
            fs = out[(size_t)n * DDIM + lane] * norm[n] * (1.0f - alpha)
               + feat0[(size_t)n * DDIM + lane] * alpha;
        }
        float acc = 0.0f;
        #pragma unroll
        for (int k = 0; k < DDIM; ++k) {
            float fsk = __shfl(fs, k, 64);
            acc = fmaf(fsk, sW[k * DDIM + lane], acc);
        }
        if (valid) out[(size_t)n * DDIM + lane] = acc;
    }
}

// ---------------- launch ----------------

static inline size_t align256(size_t x) { return (x + 255) & ~(size_t)255; }

extern "C" void kernel_launch(void* const* d_in, const int* in_sizes, int n_in,
                              void* d_out, int out_size, void* d_ws, size_t ws_size,
                              hipStream_t stream) {
    const float* feat  = (const float*)d_in[0];
    const float* feat0 = (const float*)d_in[1];
    const float* W     = (const float*)d_in[2];
    const int*   src   = (const int*)d_in[3];
    const int*   dst   = (const int*)d_in[4];
    const float* alpha = (const float*)d_in[5];
    const float* lamda = (const float*)d_in[6];
    const int*   layer = (const int*)d_in[7];
    float* out = (float*)d_out;

    int nN = in_sizes[0] / DDIM;
    int nE = in_sizes[3];
    int NS = (nN + 255) >> 8;
    int nb = (nN + SCAN_CHUNK - 1) / SCAN_CHUNK;

    // ---- new-path workspace layout ----
    size_t off = 0;
    size_t o_rowd  = off; off += align256((size_t)nN * 8);   // int2 rowdeg
    size_t o_norm  = off; off += align256((size_t)nN * 4);
    size_t o_sbase = off; off += align256((size_t)(NS + 1) * 4);
    size_t o_scnt  = off; off += align256((size_t)NS * 4);
    size_t o_wp    = off; off += align256((size_t)DDIM * DDIM * 4);
    size_t o_pidx  = off; off += align256((size_t)nE * 4);
    size_t base_sz = off;
    size_t o_featS = off; off += align256((size_t)nN * DDIM * 2);   // fp16 featS
    size_t need_t1 = off;                                 // staging aliased into featS
    size_t o_stag0 = off; off += align256((size_t)nE * 4);
    size_t need_t0 = off;                                 // staging separate (fused scale)
    size_t o_stag2 = base_sz;
    size_t need_t2 = base_sz + align256((size_t)nE * 4);  // staging separate, no featS

    bool newok = (NS >= 1 && NS <= MAXNS && nN <= (1 << 23));
    bool t0ok  = newok && ws_size >= need_t0;
    bool t1ok  = newok && ws_size >= need_t1 && ((size_t)nE * 4 <= (size_t)nN * DDIM * 2);
    bool t2ok  = newok && ws_size >= need_t2;

    if (t0ok || t1ok || t2ok) {
        int2*     rowd  = (int2*) ((char*)d_ws + o_rowd);
        float*    normv = (float*)((char*)d_ws + o_norm);
        int*      sbase = (int*)  ((char*)d_ws + o_sbase);
        int*      scnt  = (int*)  ((char*)d_ws + o_scnt);
        float*    Wp    = (float*)((char*)d_ws + o_wp);
        unsigned* pidx  = (unsigned*)((char*)d_ws + o_pidx);
        unsigned* stag  = (unsigned*)((char*)d_ws +
                              (t0ok ? o_stag0 : (t1ok ? o_featS : o_stag2)));
        float*    featS = (float*)((char*)d_ws + o_featS);

        hipMemsetAsync(scnt, 0, (size_t)NS * 4, stream);
        int pblocks = (nE + PART_EPB - 1) / PART_EPB;
        if (pblocks < 1) pblocks = 1;
        slice_count_kernel<<<pblocks, PART_TPB, 0, stream>>>(dst, scnt, nE, NS);
        slice_scan_wp_kernel<<<1, 512, 0, stream>>>(scnt, sbase, NS, nE, W, lamda, layer, Wp);
        partition_kernel<<<pblocks, PART_TPB, 0, stream>>>(src, dst, scnt, stag, nE, NS);

        int gblocks = (nN + 3) / 4;
        if (t0ok) {
            // staging separate -> fuse featS scale into bin_fill (saves a pass)
            bin_fill_scale_kernel<<<NS, 256, 0, stream>>>(
                stag, sbase, rowd, normv, pidx, (const float4*)feat, (uint2*)featS, nN);
            gather3_kernel<true><<<gblocks, 256, 0, stream>>>(
                (const void*)featS, (const float4*)feat0, normv, rowd, pidx,
                Wp, alpha, (float4*)out, nN, nE);
        } else if (t1ok) {
            bin_fill_kernel<<<NS, 256, 0, stream>>>(stag, sbase, rowd, normv, pidx, nN);
            // staging region dead after bin_fill; featS overwrites it (stream-ordered)
            scale_kernel<<<(nN + 15) / 16, 256, 0, stream>>>(
                (const float4*)feat, normv, (uint2*)featS, nN);
            gather3_kernel<true><<<gblocks, 256, 0, stream>>>(
                (const void*)featS, (const float4*)feat0, normv, rowd, pidx,
                Wp, alpha, (float4*)out, nN, nE);
        } else {
            bin_fill_kernel<<<NS, 256, 0, stream>>>(stag, sbase, rowd, normv, pidx, nN);
            gather3_kernel<false><<<gblocks, 256, 0, stream>>>(
                (const void*)feat, (const float4*)feat0, normv, rowd, pidx,
                Wp, alpha, (float4*)out, nN, nE);
        }
        return;
    }

    // ---- old CSR path (fallback) ----
    off = 0;
    size_t f_degI = off;      off += align256((size_t)nN * 4);
    size_t f_norm = off;      off += align256((size_t)nN * 4);
    size_t f_rows = off;      off += align256((size_t)nN * 4);
    size_t f_rowd = off;      off += align256((size_t)nN * 8);
    size_t f_bsum = off;      off += align256((size_t)nb * 4);
    size_t f_wp   = off;      off += align256((size_t)DDIM * DDIM * 4);
    size_t f_pidx = off;      off += align256((size_t)nE * 4);
    size_t need_csr = off;
    size_t f_featS = off;     off += align256((size_t)nN * DDIM * 2);
    size_t need_full = off;

    if (ws_size >= need_csr && nb <= SCAN_BLOCK) {
        int*   degI  = (int*)  ((char*)d_ws + f_degI);
        float* normv = (float*)((char*)d_ws + f_norm);
        int*   rows  = (int*)  ((char*)d_ws + f_rows);
        int2*  rowd  = (int2*) ((char*)d_ws + f_rowd);
        int*   bsum  = (int*)  ((char*)d_ws + f_bsum);
        float* Wp    = (float*)((char*)d_ws + f_wp);
        unsigned* pidx = (unsigned*)((char*)d_ws + f_pidx);
        bool scaled = (ws_size >= need_full);
        float* featS = (float*)((char*)d_ws + f_featS);

        hipMemsetAsync(degI, 0, (size_t)nN * 4, stream);
        int e4blocks = ((nE + 3) / 4 + 255) / 256;
        deg_int_kernel<<<e4blocks, 256, 0, stream>>>(dst, degI, nE);
        scan1_kernel<<<nb, SCAN_BLOCK, 0, stream>>>(degI, rows, normv, bsum, nN);
        scan2_wp_kernel<<<1, SCAN_BLOCK, 0, stream>>>(bsum, nb, W, lamda, layer, Wp);
        scan3_scale_kernel<<<(nN + 15) / 16, 256, 0, stream>>>(
            rows, bsum, degI, (const float4*)feat, normv,
            scaled ? (uint2*)featS : (uint2*)nullptr, rowd, nN);
        fill_kernel<<<e4blocks, 256, 0, stream>>>(src, dst, rows, pidx, nE);

        int gblocks = (nN + 3) / 4;
        if (scaled) {
            gather3_kernel<true><<<gblocks, 256, 0, stream>>>(
                (const void*)featS, (const float4*)feat0, normv, rowd, pidx,
                Wp, alpha, (float4*)out, nN, nE);
        } else {
            gather3_kernel<false><<<gblocks, 256, 0, stream>>>(
                (const void*)feat, (const float4*)feat0, normv, rowd, pidx,
                Wp, alpha, (float4*)out, nN, nE);
        }
    } else {
        float* degs = (float*)d_ws;
        size_t degs_bytes_al = align256((size_t)nN * 4);
        float* Wp = (float*)((char*)d_ws + degs_bytes_al);

        hipMemsetAsync(out, 0, (size_t)out_size * sizeof(float), stream);
        hipMemsetAsync(degs, 0, (size_t)nN * sizeof(float), stream);

        deg_kernel<<<(nE + 255) / 256, 256, 0, stream>>>(dst, degs, nE);
        norm_kernel<<<(nN + 255) / 256, 256, 0, stream>>>(degs, nN);
        wp_kernel<<<(DDIM * DDIM + 255) / 256, 256, 0, stream>>>(W, lamda, layer, Wp);

        long long tot = (long long)nE * DDIM;
        int sblocks = (int)((tot + 255) / 256);
        scatter_kernel<<<sblocks, 256, 0, stream>>>(feat, degs, src, dst, out, nE);
        final_kernel<<<2048, 256, 0, stream>>>(out, feat0, degs, Wp, alpha, nN);
    }
}

// Round 9
// 131.343 us; speedup vs baseline: 1.1951x; 1.1951x over previous
//
#include <hip/hip_runtime.h>
#include <hip/hip_fp16.h>

#define DDIM 64
#define MAXNS 2048          // max slices (nodes/256) handled by the new path
#define PART_TPB 256
#define PART_EPT 16
#define PART_EPB (PART_TPB * PART_EPT)   // 4096 edges per block

__device__ __forceinline__ float atomAddF(float* p, float v) {
    return unsafeAtomicAdd(p, v);   // HW global_atomic_add_f32 on gfx950
}

// ================= CSR BUILD: two-level counting sort by dst>>8 =================

__global__ void slice_count_kernel(const int* __restrict__ dst, int* __restrict__ sliceCnt,
                                   int nE, int NS) {
    __shared__ int lh[MAXNS];
    int t = threadIdx.x;
    int blockBase = blockIdx.x * PART_EPB;
    for (int i = t; i < NS; i += PART_TPB) lh[i] = 0;
    __syncthreads();
    #pragma unroll
    for (int c = 0; c < 4; ++c) {
        int e0 = blockBase + (c * PART_TPB + t) * 4;
        if (e0 + 3 < nE) {
            int4 b = *(const int4*)(dst + e0);
            atomicAdd(&lh[b.x >> 8], 1); atomicAdd(&lh[b.y >> 8], 1);
            atomicAdd(&lh[b.z >> 8], 1); atomicAdd(&lh[b.w >> 8], 1);
        } else {
            for (int j = 0; j < 4; ++j) {
                int e = e0 + j;
                if (e < nE) atomicAdd(&lh[dst[e] >> 8], 1);
            }
        }
    }
    __syncthreads();
    for (int i = t; i < NS; i += PART_TPB)
        if (lh[i]) atomicAdd(&sliceCnt[i], lh[i]);
}

__global__ void slice_scan_wp_kernel(int* __restrict__ scnt, int* __restrict__ sbase,
                                     int NS, int nE,
                                     const float* __restrict__ W, const float* __restrict__ lamda_p,
                                     const int* __restrict__ layer_p, float* __restrict__ Wp) {
    __shared__ int sdata[512];
    int t = threadIdx.x;
    int base = t * 4;
    int v[4];
    #pragma unroll
    for (int j = 0; j < 4; ++j) {
        int idx = base + j;
        v[j] = (idx < NS) ? scnt[idx] : 0;
    }
    int local = v[0] + v[1] + v[2] + v[3];
    sdata[t] = local;
    __syncthreads();
    for (int off = 1; off < 512; off <<= 1) {
        int y = (t >= off) ? sdata[t - off] : 0;
        __syncthreads();
        sdata[t] += y;
        __syncthreads();
    }
    int run = sdata[t] - local;
    #pragma unroll
    for (int j = 0; j < 4; ++j) {
        int idx = base + j;
        if (idx < NS) { sbase[idx] = run; scnt[idx] = run; }
        run += v[j];
    }
    if (t == 0) sbase[NS] = nE;

    float lam = lamda_p[0];
    int lb = layer_p[0];
    float layerf = (lb > 0 && lb < (1 << 23)) ? (float)lb : __int_as_float(lb);
    float beta = logf(lam / layerf + 1.0f);
    for (int i = t; i < DDIM * DDIM; i += 512) {
        int k = i >> 6, d = i & 63;
        float w = beta * W[i];
        if (k == d) w += (1.0f - beta);
        Wp[i] = w;
    }
}

__global__ void partition_kernel(const int* __restrict__ src, const int* __restrict__ dst,
                                 int* __restrict__ cursor, unsigned* __restrict__ staging,
                                 int nE, int NS) {
    __shared__ int lh[MAXNS];
    __shared__ int lbase[MAXNS];
    int t = threadIdx.x;
    int blockBase = blockIdx.x * PART_EPB;
    for (int i = t; i < NS; i += PART_TPB) lh[i] = 0;
    __syncthreads();

    int se[PART_EPT]; int de[PART_EPT];
    #pragma unroll
    for (int c = 0; c < 4; ++c) {
        int e0 = blockBase + (c * PART_TPB + t) * 4;
        if (e0 + 3 < nE) {
            int4 a = *(const int4*)(src + e0);
            int4 b = *(const int4*)(dst + e0);
            se[4*c+0] = a.x; se[4*c+1] = a.y; se[4*c+2] = a.z; se[4*c+3] = a.w;
            de[4*c+0] = b.x; de[4*c+1] = b.y; de[4*c+2] = b.z; de[4*c+3] = b.w;
        } else {
            #pragma unroll
            for (int j = 0; j < 4; ++j) {
                int e = e0 + j;
                se[4*c+j] = (e < nE) ? src[e] : 0;
                de[4*c+j] = (e < nE) ? dst[e] : -1;
            }
        }
    }
    #pragma unroll
    for (int k = 0; k < PART_EPT; ++k)
        if (de[k] >= 0) atomicAdd(&lh[de[k] >> 8], 1);
    __syncthreads();
    for (int i = t; i < NS; i += PART_TPB) {
        int c = lh[i];
        if (c) lbase[i] = atomicAdd(&cursor[i], c);
        lh[i] = 0;
    }
    __syncthreads();
    #pragma unroll
    for (int k = 0; k < PART_EPT; ++k) {
        int d = de[k];
        if (d >= 0) {
            int sl = d >> 8;
            int off = atomicAdd(&lh[sl], 1);
            staging[lbase[sl] + off] = ((unsigned)se[k] << 8) | (unsigned)(d & 255);
        }
    }
}

// Pass 4 (t1/t2 tiers): rowdeg + normv + packed pidx scatter.
__global__ void bin_fill_kernel(const unsigned* __restrict__ staging, const int* __restrict__ sbase,
                                int2* __restrict__ rowdeg, float* __restrict__ normv,
                                unsigned* __restrict__ pidx, int nN) {
    __shared__ int cnt[256];
    __shared__ int pos[256];
    int s = blockIdx.x;
    int t = threadIdx.x;
    int b0 = sbase[s], b1 = sbase[s + 1];
    cnt[t] = 0;
    __syncthreads();
    for (int j = b0 + t; j < b1; j += 256) {
        unsigned p = staging[j];
        atomicAdd(&cnt[p & 255], 1);
    }
    __syncthreads();
    int c = cnt[t];
    pos[t] = c;
    __syncthreads();
    for (int off = 1; off < 256; off <<= 1) {
        int y = (t >= off) ? pos[t - off] : 0;
        __syncthreads();
        pos[t] += y;
        __syncthreads();
    }
    int inc = pos[t];
    int exc = inc - c;
    int node = (s << 8) + t;
    if (node < nN) {
        rowdeg[node] = make_int2(b0 + inc, c);
        normv[node] = rsqrtf(fmaxf((float)c, 1.0f));
    }
    pos[t] = b0 + exc;
    __syncthreads();
    for (int j = b0 + t; j < b1; j += 256) {
        unsigned p = staging[j];
        int q = atomicAdd(&pos[p & 255], 1);
        pidx[q] = p;              // packed: src<<8 | dstLow
    }
}

// Pass 4 (t0 tier, staging NOT aliased with featS): bin_fill + fused featS scale.
__global__ void bin_fill_scale_kernel(const unsigned* __restrict__ staging, const int* __restrict__ sbase,
                                      int2* __restrict__ rowdeg, float* __restrict__ normv,
                                      unsigned* __restrict__ pidx,
                                      const float4* __restrict__ feat4, uint2* __restrict__ featS2,
                                      int nN) {
    __shared__ int cnt[256];
    __shared__ int pos[256];
    __shared__ float narr[256];
    int s = blockIdx.x;
    int t = threadIdx.x;
    int b0 = sbase[s], b1 = sbase[s + 1];
    cnt[t] = 0;
    __syncthreads();
    for (int j = b0 + t; j < b1; j += 256) {
        unsigned p = staging[j];
        atomicAdd(&cnt[p & 255], 1);
    }
    __syncthreads();
    int c = cnt[t];
    pos[t] = c;
    __syncthreads();
    for (int off = 1; off < 256; off <<= 1) {
        int y = (t >= off) ? pos[t - off] : 0;
        __syncthreads();
        pos[t] += y;
        __syncthreads();
    }
    int inc = pos[t];
    int exc = inc - c;
    int node = (s << 8) + t;
    float nv = rsqrtf(fmaxf((float)c, 1.0f));
    narr[t] = nv;
    if (node < nN) {
        rowdeg[node] = make_int2(b0 + inc, c);
        normv[node] = nv;
    }
    pos[t] = b0 + exc;
    __syncthreads();                    // also publishes narr[]
    for (int j = b0 + t; j < b1; j += 256) {
        unsigned p = staging[j];
        int q = atomicAdd(&pos[p & 255], 1);
        pidx[q] = p;
    }
    // fused featS(fp16) = feat * norm for this slice's 256 nodes (coalesced)
    for (int i = t; i < 256 * 16; i += 256) {
        int nl = i >> 4, rr = i & 15;
        int nd = (s << 8) + nl;
        if (nd < nN) {
            float sc = narr[nl];
            float4 v = feat4[(size_t)nd * 16 + rr];
            __half2 h0 = __floats2half2_rn(v.x * sc, v.y * sc);
            __half2 h1 = __floats2half2_rn(v.z * sc, v.w * sc);
            uint2 u;
            u.x = *(unsigned*)&h0;
            u.y = *(unsigned*)&h1;
            featS2[(size_t)nd * 16 + rr] = u;
        }
    }
}

// featS(fp16) = feat * norm[node] (t1 tier, staging aliased -> separate pass)
__global__ void scale_kernel(const float4* __restrict__ feat4, const float* __restrict__ normv,
                             uint2* __restrict__ featS2, int nN) {
    int b = blockIdx.x, t = threadIdx.x;
    int node = b * 16 + (t >> 4);
    int r = t & 15;
    if (node < nN) {
        float nv = normv[node];
        float4 v = feat4[(size_t)node * 16 + r];
        __half2 h0 = __floats2half2_rn(v.x * nv, v.y * nv);
        __half2 h1 = __floats2half2_rn(v.z * nv, v.w * nv);
        uint2 u;
        u.x = *(unsigned*)&h0;
        u.y = *(unsigned*)&h1;
        featS2[(size_t)node * 16 + r] = u;
    }
}

// Accumulate macros (parameter names must NOT collide with .x/.y/.z/.w tokens)
#define ACC_H(uu, ww) { \
    float2 a0 = __half22float2(*(const __half2*)&(uu).x); \
    float2 a1 = __half22float2(*(const __half2*)&(uu).y); \
    acc.x = fmaf(a0.x, ww, acc.x); acc.y = fmaf(a0.y, ww, acc.y); \
    acc.z = fmaf(a1.x, ww, acc.z); acc.w = fmaf(a1.y, ww, acc.w); }
#define ACC_F(vv, ww) { \
    acc.x = fmaf((vv).x, ww, acc.x); acc.y = fmaf((vv).y, ww, acc.y); \
    acc.z = fmaf((vv).z, ww, acc.z); acc.w = fmaf((vv).w, ww, acc.w); }

// ---------------- fused gather + epilogue (wave per node, 4x16 lane layout) ----------------
// UNCHANGED from r7; grid MUST be capped at 8192 blocks (r8 uncapped ->
// 25000 blocks -> 1 node/wave: sW staging x3, pipeline dead, gather +30%).
template<bool HALF>
__global__ void gather3_kernel(const void* __restrict__ featv_, const float4* __restrict__ feat04,
                               const float* __restrict__ normv, const int2* __restrict__ rowdeg,
                               const unsigned* __restrict__ pidx,
                               const float* __restrict__ Wp, const float* __restrict__ alpha_p,
                               float4* __restrict__ out4, int nN, int nE) {
    __shared__ float4 sW[DDIM * 16];   // 16 KiB, XOR-swizzled
    const float4* Wp4 = (const float4*)Wp;
    for (int i = threadIdx.x; i < DDIM * 16; i += blockDim.x) {
        sW[(i & ~15) | ((i & 15) ^ ((i >> 8) & 3))] = Wp4[i];
    }
    __syncthreads();

    const float4* featF = (const float4*)featv_;
    const uint2*  featH = (const uint2*)featv_;

    int lane = threadIdx.x & 63;
    int w = threadIdx.x >> 6;
    int g = lane >> 4;
    int r = lane & 15;
    float alpha = alpha_p[0];
    int step = gridDim.x * 4;
    int nEm1 = nE - 1;

    int n = blockIdx.x * 4 + w;
    if (n >= nN) return;

    int2 rd = rowdeg[n];
    int pj = rd.x - rd.y + lane;
    unsigned pv = pidx[pj > nEm1 ? nEm1 : (pj < 0 ? 0 : pj)];
    int n1 = n + step;
    int2 rd1 = make_int2(0, 0);
    if (n1 < nN) rd1 = rowdeg[n1];

    while (true) {
        unsigned pv1 = 0u;
        if (n1 < nN) {
            int pj1 = rd1.x - rd1.y + lane;
            pv1 = pidx[pj1 > nEm1 ? nEm1 : (pj1 < 0 ? 0 : pj1)];
        }
        int n2 = n1 + step;
        int2 rd2 = make_int2(0, 0);
        if (n2 < nN) rd2 = rowdeg[n2];

        float4 f0 = feat04[(size_t)n * 16 + r];

        int end = rd.x;
        int start = end - rd.y;

        float4 acc = make_float4(0.f, 0.f, 0.f, 0.f);

        for (int j0 = start; j0 < end; j0 += 64) {
            int m = end - j0; if (m > 64) m = 64;
            unsigned pcur;
            if (j0 == start) {
                pcur = pv;
            } else {
                int cj = j0 + lane;
                pcur = pidx[cj > nEm1 ? nEm1 : cj];
            }
            int sIdx = (int)(pcur >> 8);
            float nv = 1.0f;
            if (!HALF) nv = normv[sIdx];
            int nt = (m + 3) >> 2;
            int t = 0;
            for (; t + 3 <= nt; t += 3) {
                int e0 = 4 * t + g, e1 = e0 + 4, e2 = e0 + 8;
                int s0 = __shfl(sIdx, e0, 64);
                int s1 = __shfl(sIdx, e1, 64);
                int s2 = __shfl(sIdx, e2, 64);
                float w0 = (e0 < m) ? 1.0f : 0.0f;
                float w1 = (e1 < m) ? 1.0f : 0.0f;
                float w2 = (e2 < m) ? 1.0f : 0.0f;
                if (HALF) {
                    uint2 ua = featH[(size_t)s0 * 16 + r];
                    uint2 ub = featH[(size_t)s1 * 16 + r];
                    uint2 uc = featH[(size_t)s2 * 16 + r];
                    ACC_H(ua, w0) ACC_H(ub, w1) ACC_H(uc, w2)
                } else {
                    w0 *= __shfl(nv, e0, 64);
                    w1 *= __shfl(nv, e1, 64);
                    w2 *= __shfl(nv, e2, 64);
                    float4 fa = featF[(size_t)s0 * 16 + r];
                    float4 fb = featF[(size_t)s1 * 16 + r];
                    float4 fc = featF[(size_t)s2 * 16 + r];
                    ACC_F(fa, w0) ACC_F(fb, w1) ACC_F(fc, w2)
                }
            }
            for (; t + 2 <= nt; t += 2) {
                int e0 = 4 * t + g, e1 = e0 + 4;
                int s0 = __shfl(sIdx, e0, 64);
                int s1 = __shfl(sIdx, e1, 64);
                float w0 = (e0 < m) ? 1.0f : 0.0f;
                float w1 = (e1 < m) ? 1.0f : 0.0f;
                if (HALF) {
                    uint2 ua = featH[(size_t)s0 * 16 + r];
                    uint2 ub = featH[(size_t)s1 * 16 + r];
                    ACC_H(ua, w0) ACC_H(ub, w1)
                } else {
                    w0 *= __shfl(nv, e0, 64);
                    w1 *= __shfl(nv, e1, 64);
                    float4 fa = featF[(size_t)s0 * 16 + r];
                    float4 fb = featF[(size_t)s1 * 16 + r];
                    ACC_F(fa, w0) ACC_F(fb, w1)
                }
            }
            for (; t < nt; ++t) {
                int e = 4 * t + g;
                int s = __shfl(sIdx, e, 64);
                float w0 = (e < m) ? 1.0f : 0.0f;
                if (HALF) {
                    uint2 ua = featH[(size_t)s * 16 + r];
                    ACC_H(ua, w0)
                } else {
                    w0 *= __shfl(nv, e, 64);
                    float4 fa = featF[(size_t)s * 16 + r];
                    ACC_F(fa, w0)
                }
            }
        }

        acc.x += __shfl_xor(acc.x, 16, 64); acc.y += __shfl_xor(acc.y, 16, 64);
        acc.z += __shfl_xor(acc.z, 16, 64); acc.w += __shfl_xor(acc.w, 16, 64);
        acc.x += __shfl_xor(acc.x, 32, 64); acc.y += __shfl_xor(acc.y, 32, 64);
        acc.z += __shfl_xor(acc.z, 32, 64); acc.w += __shfl_xor(acc.w, 32, 64);

        float sn = normv[n] * (1.0f - alpha);
        float4 fs;
        fs.x = fmaf(acc.x, sn, f0.x * alpha);
        fs.y = fmaf(acc.y, sn, f0.y * alpha);
        fs.z = fmaf(acc.z, sn, f0.z * alpha);
        fs.w = fmaf(acc.w, sn, f0.w * alpha);

        float4 res = make_float4(0.f, 0.f, 0.f, 0.f);
        #pragma unroll
        for (int kk = 0; kk < 16; ++kk) {
            int srcLane = 4 * g + (kk >> 2);
            float fscomp = ((kk & 3) == 0) ? fs.x : ((kk & 3) == 1) ? fs.y
                         : ((kk & 3) == 2) ? fs.z : fs.w;
            float fsk = __shfl(fscomp, srcLane, 64);
            float4 wv = sW[(16 * g + kk) * 16 + (r ^ g)];
            res.x = fmaf(fsk, wv.x, res.x);
            res.y = fmaf(fsk, wv.y, res.y);
            res.z = fmaf(fsk, wv.z, res.z);
            res.w = fmaf(fsk, wv.w, res.w);
        }
        res.x += __shfl_xor(res.x, 16, 64); res.y += __shfl_xor(res.y, 16, 64);
        res.z += __shfl_xor(res.z, 16, 64); res.w += __shfl_xor(res.w, 16, 64);
        res.x += __shfl_xor(res.x, 32, 64); res.y += __shfl_xor(res.y, 32, 64);
        res.z += __shfl_xor(res.z, 32, 64); res.w += __shfl_xor(res.w, 32, 64);

        if (g == 0) out4[(size_t)n * 16 + r] = res;

        if (n1 >= nN) break;
        n = n1; rd = rd1; pv = pv1;
        n1 = n2; rd1 = rd2;
    }
}

// ================= OLD CSR BUILD (fallback tier) =================

__global__ void deg_int_kernel(const int* __restrict__ dst, int* __restrict__ degI, int nE) {
    int i = blockIdx.x * blockDim.x + threadIdx.x;
    int base = i * 4;
    if (base + 3 < nE) {
        int4 d = *(const int4*)(dst + base);
        atomicAdd(&degI[d.x], 1); atomicAdd(&degI[d.y], 1);
        atomicAdd(&degI[d.z], 1); atomicAdd(&degI[d.w], 1);
    } else {
        for (int j = base; j < nE; ++j) atomicAdd(&degI[dst[j]], 1);
    }
}

#define SCAN_BLOCK 256
#define SCAN_CHUNK 1024

__global__ void scan1_kernel(const int* __restrict__ degI, int* __restrict__ row_start,
                             float* __restrict__ normv, int* __restrict__ blockSums, int nN) {
    __shared__ int sdata[SCAN_BLOCK];
    int t = threadIdx.x;
    int base = blockIdx.x * SCAN_CHUNK + t * 4;
    int v[4];
    #pragma unroll
    for (int j = 0; j < 4; ++j) {
        int idx = base + j;
        v[j] = (idx < nN) ? degI[idx] : 0;
    }
    int local = v[0] + v[1] + v[2] + v[3];
    sdata[t] = local;
    __syncthreads();
    for (int off = 1; off < SCAN_BLOCK; off <<= 1) {
        int y = (t >= off) ? sdata[t - off] : 0;
        __syncthreads();
        sdata[t] += y;
        __syncthreads();
    }
    int inc = sdata[t];
    int exc = inc - local;
    if (t == SCAN_BLOCK - 1) blockSums[blockIdx.x] = inc;
    int run = exc;
    #pragma unroll
    for (int j = 0; j < 4; ++j) {
        int idx = base + j;
        if (idx < nN) {
            row_start[idx] = run;
            normv[idx] = rsqrtf(fmaxf((float)v[j], 1.0f));
        }
        run += v[j];
    }
}

__global__ void scan2_wp_kernel(int* __restrict__ blockSums, int nb,
                                const float* __restrict__ W, const float* __restrict__ lamda_p,
                                const int* __restrict__ layer_p, float* __restrict__ Wp) {
    __shared__ int sdata[SCAN_BLOCK];
    int t = threadIdx.x;
    int v = (t < nb) ? blockSums[t] : 0;
    sdata[t] = v;
    __syncthreads();
    for (int off = 1; off < SCAN_BLOCK; off <<= 1) {
        int y = (t >= off) ? sdata[t - off] : 0;
        __syncthreads();
        sdata[t] += y;
        __syncthreads();
    }
    if (t < nb) blockSums[t] = sdata[t] - v;

    float lam = lamda_p[0];
    int lb = layer_p[0];
    float layerf = (lb > 0 && lb < (1 << 23)) ? (float)lb : __int_as_float(lb);
    float beta = logf(lam / layerf + 1.0f);
    for (int i = t; i < DDIM * DDIM; i += SCAN_BLOCK) {
        int k = i >> 6, d = i & 63;
        float w = beta * W[i];
        if (k == d) w += (1.0f - beta);
        Wp[i] = w;
    }
}

// add block offsets to row_start, build rowdeg, optionally produce featS(fp16)
__global__ void scan3_scale_kernel(int* __restrict__ row_start, const int* __restrict__ blockSums,
                                   const int* __restrict__ degI,
                                   const float4* __restrict__ feat4, const float* __restrict__ normv,
                                   uint2* __restrict__ featS2, int2* __restrict__ rowdeg, int nN) {
    int b = blockIdx.x, t = threadIdx.x;
    int node = b * 16 + (t >> 4);
    int r = t & 15;
    if (featS2 != nullptr && node < nN) {
        float nv = normv[node];
        float4 v = feat4[(size_t)node * 16 + r];
        __half2 h0 = __floats2half2_rn(v.x * nv, v.y * nv);
        __half2 h1 = __floats2half2_rn(v.z * nv, v.w * nv);
        uint2 u;
        u.x = *(unsigned*)&h0;
        u.y = *(unsigned*)&h1;
        featS2[(size_t)node * 16 + r] = u;
    }
    if (t < 16) {
        int n2 = b * 16 + t;
        if (n2 < nN) {
            int rs = row_start[n2] + blockSums[n2 >> 10];
            int dg = degI[n2];
            row_start[n2] = rs;
            rowdeg[n2] = make_int2(rs + dg, dg);   // row END after fill
        }
    }
}

// packed fill: pidx entry = src<<8 | dstLow
__global__ void fill_kernel(const int* __restrict__ src, const int* __restrict__ dst,
                            int* __restrict__ row_start, unsigned* __restrict__ pidx, int nE) {
    int i = blockIdx.x * blockDim.x + threadIdx.x;
    int base = i * 4;
    if (base + 3 < nE) {
        int4 s = *(const int4*)(src + base);
        int4 d = *(const int4*)(dst + base);
        pidx[atomicAdd(&row_start[d.x], 1)] = ((unsigned)s.x << 8) | (unsigned)(d.x & 255);
        pidx[atomicAdd(&row_start[d.y], 1)] = ((unsigned)s.y << 8) | (unsigned)(d.y & 255);
        pidx[atomicAdd(&row_start[d.z], 1)] = ((unsigned)s.z << 8) | (unsigned)(d.z & 255);
        pidx[atomicAdd(&row_start[d.w], 1)] = ((unsigned)s.w << 8) | (unsigned)(d.w & 255);
    } else {
        for (int j = base; j < nE; ++j) {
            int tt = dst[j];
            int p = atomicAdd(&row_start[tt], 1);
            pidx[p] = ((unsigned)src[j] << 8) | (unsigned)(tt & 255);
        }
    }
}

// ---------------- last-resort fallback (atomic scatter path) ----------------

__global__ void deg_kernel(const int* __restrict__ dst, float* __restrict__ degs, int nE) {
    int i = blockIdx.x * blockDim.x + threadIdx.x;
    if (i < nE) atomAddF(&degs[dst[i]], 1.0f);
}

__global__ void norm_kernel(float* degs, int nN) {
    int i = blockIdx.x * blockDim.x + threadIdx.x;
    if (i < nN) degs[i] = rsqrtf(fmaxf(degs[i], 1.0f));
}

__global__ void wp_kernel(const float* __restrict__ W, const float* __restrict__ lamda_p,
                          const int* __restrict__ layer_p, float* __restrict__ Wp) {
    int i = blockIdx.x * blockDim.x + threadIdx.x;
    if (i < DDIM * DDIM) {
        float lam = lamda_p[0];
        int lb = layer_p[0];
        float layerf = (lb > 0 && lb < (1 << 23)) ? (float)lb : __int_as_float(lb);
        float beta = logf(lam / layerf + 1.0f);
        int k = i >> 6, d = i & 63;
        float w = beta * W[i];
        if (k == d) w += (1.0f - beta);
        Wp[i] = w;
    }
}

__global__ void scatter_kernel(const float* __restrict__ feat, const float* __restrict__ norm,
                               const int* __restrict__ src, const int* __restrict__ dst,
                               float* __restrict__ accum, int nE) {
    long long gid = (long long)blockIdx.x * blockDim.x + threadIdx.x;
    int e = (int)(gid >> 6);
    int d = (int)(gid & 63);
    if (e < nE) {
        int s = src[e];
        int t = dst[e];
        float v = feat[(size_t)s * DDIM + d] * norm[s];
        atomAddF(&accum[(size_t)t * DDIM + d], v);
    }
}

__global__ void final_kernel(float* __restrict__ out, const float* __restrict__ feat0,
                             const float* __restrict__ norm, const float* __restrict__ Wp,
                             const float* __restrict__ alpha_p, int nN) {
    __shared__ float sW[DDIM * DDIM];
    for (int i = threadIdx.x; i < DDIM * DDIM; i += blockDim.x) sW[i] = Wp[i];
    __syncthreads();
    float alpha = alpha_p[0];
    int lane = threadIdx.x & 63;
    int w = threadIdx.x >> 6;
    int wavesPerBlock = blockDim.x >> 6;
    int nGroups = (nN + wavesPerBlock - 1) / wavesPerBlock;
    for (int gi = blockIdx.x; gi < nGroups; gi += gridDim.x) {
        int n = gi * wavesPerBlock + w;
        bool valid = n < nN;
        float fs = 0.0f;
        if (valid) {
            fs = out[(size_t)n * DDIM + lane] * norm[n] * (1.0f - alpha)
               + feat0[(size_t)n * DDIM + lane] * alpha;
        }
        float acc = 0.0f;
        #pragma unroll
        for (int k = 0; k < DDIM; ++k) {
            float fsk = __shfl(fs, k, 64);
            acc = fmaf(fsk, sW[k * DDIM + lane], acc);
        }
        if (valid) out[(size_t)n * DDIM + lane] = acc;
    }
}

// ---------------- launch ----------------

static inline size_t align256(size_t x) { return (x + 255) & ~(size_t)255; }

extern "C" void kernel_launch(void* const* d_in, const int* in_sizes, int n_in,
                              void* d_out, int out_size, void* d_ws, size_t ws_size,
                              hipStream_t stream) {
    const float* feat  = (const float*)d_in[0];
    const float* feat0 = (const float*)d_in[1];
    const float* W     = (const float*)d_in[2];
    const int*   src   = (const int*)d_in[3];
    const int*   dst   = (const int*)d_in[4];
    const float* alpha = (const float*)d_in[5];
    const float* lamda = (const float*)d_in[6];
    const int*   layer = (const int*)d_in[7];
    float* out = (float*)d_out;

    int nN = in_sizes[0] / DDIM;
    int nE = in_sizes[3];
    int NS = (nN + 255) >> 8;
    int nb = (nN + SCAN_CHUNK - 1) / SCAN_CHUNK;

    // ---- new-path workspace layout ----
    size_t off = 0;
    size_t o_rowd  = off; off += align256((size_t)nN * 8);   // int2 rowdeg
    size_t o_norm  = off; off += align256((size_t)nN * 4);
    size_t o_sbase = off; off += align256((size_t)(NS + 1) * 4);
    size_t o_scnt  = off; off += align256((size_t)NS * 4);
    size_t o_wp    = off; off += align256((size_t)DDIM * DDIM * 4);
    size_t o_pidx  = off; off += align256((size_t)nE * 4);
    size_t base_sz = off;
    size_t o_featS = off; off += align256((size_t)nN * DDIM * 2);   // fp16 featS
    size_t need_t1 = off;                                 // staging aliased into featS
    size_t o_stag0 = off; off += align256((size_t)nE * 4);
    size_t need_t0 = off;                                 // staging separate (fused scale)
    size_t o_stag2 = base_sz;
    size_t need_t2 = base_sz + align256((size_t)nE * 4);  // staging separate, no featS

    bool newok = (NS >= 1 && NS <= MAXNS && nN <= (1 << 23));
    bool t0ok  = newok && ws_size >= need_t0;
    bool t1ok  = newok && ws_size >= need_t1 && ((size_t)nE * 4 <= (size_t)nN * DDIM * 2);
    bool t2ok  = newok && ws_size >= need_t2;

    if (t0ok || t1ok || t2ok) {
        int2*     rowd  = (int2*) ((char*)d_ws + o_rowd);
        float*    normv = (float*)((char*)d_ws + o_norm);
        int*      sbase = (int*)  ((char*)d_ws + o_sbase);
        int*      scnt  = (int*)  ((char*)d_ws + o_scnt);
        float*    Wp    = (float*)((char*)d_ws + o_wp);
        unsigned* pidx  = (unsigned*)((char*)d_ws + o_pidx);
        unsigned* stag  = (unsigned*)((char*)d_ws +
                              (t0ok ? o_stag0 : (t1ok ? o_featS : o_stag2)));
        float*    featS = (float*)((char*)d_ws + o_featS);

        hipMemsetAsync(scnt, 0, (size_t)NS * 4, stream);
        int pblocks = (nE + PART_EPB - 1) / PART_EPB;
        if (pblocks < 1) pblocks = 1;
        slice_count_kernel<<<pblocks, PART_TPB, 0, stream>>>(dst, scnt, nE, NS);
        slice_scan_wp_kernel<<<1, 512, 0, stream>>>(scnt, sbase, NS, nE, W, lamda, layer, Wp);
        partition_kernel<<<pblocks, PART_TPB, 0, stream>>>(src, dst, scnt, stag, nE, NS);

        int gblocks = (nN + 3) / 4;
        if (gblocks > 8192) gblocks = 8192;   // r8 lesson: uncapped = 1 node/wave = +30% gather
        if (t0ok) {
            // staging separate -> fuse featS scale into bin_fill (saves a pass)
            bin_fill_scale_kernel<<<NS, 256, 0, stream>>>(
                stag, sbase, rowd, normv, pidx, (const float4*)feat, (uint2*)featS, nN);
            gather3_kernel<true><<<gblocks, 256, 0, stream>>>(
                (const void*)featS, (const float4*)feat0, normv, rowd, pidx,
                Wp, alpha, (float4*)out, nN, nE);
        } else if (t1ok) {
            bin_fill_kernel<<<NS, 256, 0, stream>>>(stag, sbase, rowd, normv, pidx, nN);
            // staging region dead after bin_fill; featS overwrites it (stream-ordered)
            scale_kernel<<<(nN + 15) / 16, 256, 0, stream>>>(
                (const float4*)feat, normv, (uint2*)featS, nN);
            gather3_kernel<true><<<gblocks, 256, 0, stream>>>(
                (const void*)featS, (const float4*)feat0, normv, rowd, pidx,
                Wp, alpha, (float4*)out, nN, nE);
        } else {
            bin_fill_kernel<<<NS, 256, 0, stream>>>(stag, sbase, rowd, normv, pidx, nN);
            gather3_kernel<false><<<gblocks, 256, 0, stream>>>(
                (const void*)feat, (const float4*)feat0, normv, rowd, pidx,
                Wp, alpha, (float4*)out, nN, nE);
        }
        return;
    }

    // ---- old CSR path (fallback) ----
    off = 0;
    size_t f_degI = off;      off += align256((size_t)nN * 4);
    size_t f_norm = off;      off += align256((size_t)nN * 4);
    size_t f_rows = off;      off += align256((size_t)nN * 4);
    size_t f_rowd = off;      off += align256((size_t)nN * 8);
    size_t f_bsum = off;      off += align256((size_t)nb * 4);
    size_t f_wp   = off;      off += align256((size_t)DDIM * DDIM * 4);
    size_t f_pidx = off;      off += align256((size_t)nE * 4);
    size_t need_csr = off;
    size_t f_featS = off;     off += align256((size_t)nN * DDIM * 2);
    size_t need_full = off;

    if (ws_size >= need_csr && nb <= SCAN_BLOCK) {
        int*   degI  = (int*)  ((char*)d_ws + f_degI);
        float* normv = (float*)((char*)d_ws + f_norm);
        int*   rows  = (int*)  ((char*)d_ws + f_rows);
        int2*  rowd  = (int2*) ((char*)d_ws + f_rowd);
        int*   bsum  = (int*)  ((char*)d_ws + f_bsum);
        float* Wp    = (float*)((char*)d_ws + f_wp);
        unsigned* pidx = (unsigned*)((char*)d_ws + f_pidx);
        bool scaled = (ws_size >= need_full);
        float* featS = (float*)((char*)d_ws + f_featS);

        hipMemsetAsync(degI, 0, (size_t)nN * 4, stream);
        int e4blocks = ((nE + 3) / 4 + 255) / 256;
        deg_int_kernel<<<e4blocks, 256, 0, stream>>>(dst, degI, nE);
        scan1_kernel<<<nb, SCAN_BLOCK, 0, stream>>>(degI, rows, normv, bsum, nN);
        scan2_wp_kernel<<<1, SCAN_BLOCK, 0, stream>>>(bsum, nb, W, lamda, layer, Wp);
        scan3_scale_kernel<<<(nN + 15) / 16, 256, 0, stream>>>(
            rows, bsum, degI, (const float4*)feat, normv,
            scaled ? (uint2*)featS : (uint2*)nullptr, rowd, nN);
        fill_kernel<<<e4blocks, 256, 0, stream>>>(src, dst, rows, pidx, nE);

        int gblocks = (nN + 3) / 4;
        if (gblocks > 8192) gblocks = 8192;
        if (scaled) {
            gather3_kernel<true><<<gblocks, 256, 0, stream>>>(
                (const void*)featS, (const float4*)feat0, normv, rowd, pidx,
                Wp, alpha, (float4*)out, nN, nE);
        } else {
            gather3_kernel<false><<<gblocks, 256, 0, stream>>>(
                (const void*)feat, (const float4*)feat0, normv, rowd, pidx,
                Wp, alpha, (float4*)out, nN, nE);
        }
    } else {
        float* degs = (float*)d_ws;
        size_t degs_bytes_al = align256((size_t)nN * 4);
        float* Wp = (float*)((char*)d_ws + degs_bytes_al);

        hipMemsetAsync(out, 0, (size_t)out_size * sizeof(float), stream);
        hipMemsetAsync(degs, 0, (size_t)nN * sizeof(float), stream);

        deg_kernel<<<(nE + 255) / 256, 256, 0, stream>>>(dst, degs, nE);
        norm_kernel<<<(nN + 255) / 256, 256, 0, stream>>>(degs, nN);
        wp_kernel<<<(DDIM * DDIM + 255) / 256, 256, 0, stream>>>(W, lamda, layer, Wp);

        long long tot = (long long)nE * DDIM;
        int sblocks = (int)((tot + 255) / 256);
        scatter_kernel<<<sblocks, 256, 0, stream>>>(feat, degs, src, dst, out, nE);
        final_kernel<<<2048, 256, 0, stream>>>(out, feat0, degs, Wp, alpha, nN);
    }
}